// Round 3
// baseline (72.729 us; speedup 1.0000x reference)
//
#include <hip/hip_runtime.h>
#include <cstddef>

#define NB 64
#define NA 5
#define NC 20
#define NH 64
#define NW 64
#define MAXB 50
#define HWSZ (NH * NW)
#define CELLS 4
#define GBY 4                        // HWSZ / (256*CELLS)
#define NBB (NB * NA * GBY)          // 1280 B-blocks
#define NPART (NBB + NB)             // + 64 A-blocks = 1344

__constant__ float c_aw[NA] = {1.3221f, 3.19275f, 5.05587f, 9.47112f, 11.2364f};
__constant__ float c_ah[NA] = {1.73145f, 4.00944f, 8.09892f, 4.84053f, 10.0071f};

__device__ __forceinline__ float sigmoidf_(float v) {
    return 1.f / (1.f + __expf(-v));
}

__global__ __launch_bounds__(256) void region_loss_fused(const float* __restrict__ out,
                                                         const float* __restrict__ tgt,
                                                         float* __restrict__ partials,
                                                         int* __restrict__ ctr,
                                                         float* __restrict__ outp) {
    const int bid = blockIdx.x;
    const int t = threadIdx.x;

    __shared__ __align__(16) float sbox[MAXB][8];  // B: xlo,xhi,ylo,yhi,0.375*area
    __shared__ float s_cls[MAXB], s_gx[MAXB], s_gy[MAXB], s_gw[MAXB], s_gh[MAXB];
    __shared__ int s_flat[MAXB], s_bestn[MAXB];
    __shared__ int s_nv;
    __shared__ float sred[4];
    __shared__ int s_last;

    float blocksum = 0.f;

    if (bid < NBB) {
        // ---------------- B: default no-obj conf loss ----------------
        const int ba = bid >> 2;            // 0..319 = b*NA + a
        const int yc = bid & 3;
        const int b = ba / NA, a = ba % NA;
        const int hw0 = yc * (256 * CELLS);

        // prefix validity via ballot (wave 0)
        if (t < 64) {
            float xv = (t < MAXB) ? tgt[(size_t)b * (MAXB * 5) + t * 5 + 1] : 0.f;
            unsigned long long mk = __ballot(xv != 0.f);
            if (t == 0) {
                unsigned long long inv = (~mk) & ((1ull << MAXB) - 1ull);
                s_nv = inv ? (__ffsll(inv) - 1) : MAXB;
            }
        }
        if (t < MAXB) {
            const float* tp = tgt + (size_t)b * (MAXB * 5) + t * 5;
            float gx = tp[1] * (float)NW, gy = tp[2] * (float)NH;
            float gw = tp[3] * (float)NW, gh = tp[4] * (float)NH;
            sbox[t][0] = gx - 0.5f * gw;
            sbox[t][1] = gx + 0.5f * gw;
            sbox[t][2] = gy - 0.5f * gh;
            sbox[t][3] = gy + 0.5f * gh;
            sbox[t][4] = 0.375f * gw * gh;
        }

        float pxlo[CELLS], pxhi[CELLS], pylo[CELLS], pyhi[CELLS];
        float m[CELLS], rhs[CELLS], hc[CELLS];
        const float aw = c_aw[a], ah = c_ah[a];
        const float* p0 = out + (size_t)ba * 25 * HWSZ + hw0 + t;
#pragma unroll
        for (int c = 0; c < CELLS; ++c) {
            const int hw = hw0 + c * 256 + t;
            const float fi = (float)(hw & (NW - 1));
            const float fj = (float)(hw >> 6);
            const float* p = p0 + c * 256;
            float px = sigmoidf_(p[0]) + fi;
            float py = sigmoidf_(p[HWSZ]) + fj;
            float pw = __expf(p[2 * HWSZ]) * aw;
            float ph = __expf(p[3 * HWSZ]) * ah;
            float cf = sigmoidf_(p[4 * HWSZ]);
            pxlo[c] = px - 0.5f * pw; pxhi[c] = px + 0.5f * pw;
            pylo[c] = py - 0.5f * ph; pyhi[c] = py + 0.5f * ph;
            rhs[c] = 0.375f * pw * ph;
            hc[c]  = 0.5f * cf * cf;
            m[c]   = -1e30f;
        }
        __syncthreads();

        const int nv = s_nv;
        for (int t2 = 0; t2 < nv; ++t2) {
            const float4 bb = *reinterpret_cast<const float4*>(&sbox[t2][0]);
            const float s2 = sbox[t2][4];
#pragma unroll
            for (int c = 0; c < CELLS; ++c) {
                float cw = fminf(pxhi[c], bb.y) - fmaxf(pxlo[c], bb.x);
                float ch = fminf(pyhi[c], bb.w) - fmaxf(pylo[c], bb.z);
                float ca = fmaxf(cw, 0.f) * fmaxf(ch, 0.f);
                m[c] = fmaxf(m[c], ca - s2);   // sil <=> max > 0.375*parea
            }
        }

        float v = 0.f;
#pragma unroll
        for (int c = 0; c < CELLS; ++c) v += (m[c] > rhs[c]) ? 0.f : hc[c];

        for (int off = 32; off; off >>= 1) v += __shfl_down(v, off, 64);
        if ((t & 63) == 0) sred[t >> 6] = v;
        __syncthreads();
        if (t == 0) blocksum = sred[0] + sred[1] + sred[2] + sred[3];
    } else {
        // ---------------- A: assigned-cell terms ----------------
        const int b = bid - NBB;
        if (t < 64) {
            float xv = (t < MAXB) ? tgt[(size_t)b * (MAXB * 5) + t * 5 + 1] : 0.f;
            unsigned long long mk = __ballot(xv != 0.f);
            if (t == 0) {
                unsigned long long inv = (~mk) & ((1ull << MAXB) - 1ull);
                s_nv = inv ? (__ffsll(inv) - 1) : MAXB;
            }
        }
        if (t < MAXB) {
            const float* tp = tgt + (size_t)b * (MAXB * 5) + t * 5;
            s_cls[t] = tp[0];
            s_gx[t] = tp[1] * NW; s_gy[t] = tp[2] * NH;
            s_gw[t] = tp[3] * NW; s_gh[t] = tp[4] * NH;
        }
        __syncthreads();
        const int nv = s_nv;

        if (t < MAXB) {
            if (t < nv) {
                float gw = s_gw[t], gh = s_gh[t];
                float best = -1.f; int bn = 0;
                for (int a = 0; a < NA; ++a) {
                    float ca = fminf(c_aw[a], gw) * fminf(c_ah[a], gh);
                    float ua = c_aw[a] * c_ah[a] + gw * gh - ca;
                    float iou = ca / ua;
                    if (iou > best) { best = iou; bn = a; }
                }
                int gi = (int)s_gx[t], gj = (int)s_gy[t];
                s_bestn[t] = bn;
                s_flat[t] = (bn * NH + gj) * NW + gi;
            } else {
                s_flat[t] = -1 - t;
            }
        }
        __syncthreads();

        float loss = 0.f;
        if (t < nv) {
            bool winner = true;
            const int myf = s_flat[t];
            for (int t2 = t + 1; t2 < nv; ++t2) winner = winner && (s_flat[t2] != myf);
            if (winner) {
                const int a = s_bestn[t];
                const int gi = myf & (NW - 1);
                const int gj = (myf >> 6) & (NH - 1);
                const size_t base = (((size_t)b * NA + a) * 25) * HWSZ + gj * NW + gi;
                float x = sigmoidf_(out[base]);
                float y = sigmoidf_(out[base + HWSZ]);
                float w = __expf(out[base + 2 * HWSZ]);
                float h = __expf(out[base + 3 * HWSZ]);
                float conf = sigmoidf_(out[base + 4 * HWSZ]);

                float gx = s_gx[t], gy = s_gy[t], gw = s_gw[t], gh = s_gh[t];
                float tx = gx - (float)gi, ty = gy - (float)gj;
                float tw = gw / c_aw[a], th = gh / c_ah[a];
                float dx = x - tx, dy = y - ty, dw = w - tw, dh = h - th;
                loss += 0.5f * (dx * dx + dy * dy + dw * dw + dh * dh);

                float px = x + (float)gi, py = y + (float)gj;
                float pw = w * c_aw[a], ph = h * c_ah[a];
                float pxlo = px - 0.5f * pw, pxhi = px + 0.5f * pw;
                float pylo = py - 0.5f * ph, pyhi = py + 0.5f * ph;
                float parea = pw * ph;

                {   // assigned conf term minus what B added
                    float cw  = fminf(pxhi, gx + 0.5f * gw) - fmaxf(pxlo, gx - 0.5f * gw);
                    float chh = fminf(pyhi, gy + 0.5f * gh) - fmaxf(pylo, gy - 0.5f * gh);
                    float ca  = fmaxf(cw, 0.f) * fmaxf(chh, 0.f);
                    float ua  = parea + gw * gh - ca;
                    float tconf = ca / ua;
                    float mm = -1e30f;
                    for (int t2 = 0; t2 < nv; ++t2) {
                        float gw2 = s_gw[t2], gh2 = s_gh[t2];
                        float cw2 = fminf(pxhi, s_gx[t2] + 0.5f * gw2) -
                                    fmaxf(pxlo, s_gx[t2] - 0.5f * gw2);
                        float ch2 = fminf(pyhi, s_gy[t2] + 0.5f * gh2) -
                                    fmaxf(pylo, s_gy[t2] - 0.5f * gh2);
                        float ca2 = fmaxf(cw2, 0.f) * fmaxf(ch2, 0.f);
                        mm = fmaxf(mm, ca2 - 0.375f * gw2 * gh2);
                    }
                    bool sil = mm > 0.375f * parea;
                    float base_c = sil ? 0.f : 0.5f * conf * conf;
                    float dc = conf - tconf;
                    loss += 0.5f * dc * dc - base_c;
                }

                {   // class cross-entropy
                    const int lab = (int)s_cls[t];
                    float mmax = -1e30f, llab = 0.f;
                    for (int c = 0; c < NC; ++c) {
                        float l = out[base + (size_t)(5 + c) * HWSZ];
                        mmax = fmaxf(mmax, l);
                        if (c == lab) llab = l;
                    }
                    float se = 0.f;
                    for (int c = 0; c < NC; ++c)
                        se += __expf(out[base + (size_t)(5 + c) * HWSZ] - mmax);
                    loss += -(llab - mmax - logf(se));
                }
            }
        }
        for (int off = 32; off; off >>= 1) loss += __shfl_down(loss, off, 64);
        if (t == 0) blocksum = loss;
    }

    // ---------------- common tail: last block reduces ----------------
    if (t == 0) {
        partials[bid] = blocksum;
        __threadfence();   // agent-scope release of the partial store
        int old = __hip_atomic_fetch_add(ctr, 1, __ATOMIC_ACQ_REL, __HIP_MEMORY_SCOPE_AGENT);
        s_last = (old == NPART - 1) ? 1 : 0;
    }
    __syncthreads();
    if (s_last) {
        float v = 0.f;
        for (int i = t; i < NPART; i += 256)
            v += __hip_atomic_load(&partials[i], __ATOMIC_RELAXED, __HIP_MEMORY_SCOPE_AGENT);
        for (int off = 32; off; off >>= 1) v += __shfl_down(v, off, 64);
        if ((t & 63) == 0) sred[t >> 6] = v;
        __syncthreads();
        if (t == 0) outp[0] = sred[0] + sred[1] + sred[2] + sred[3];
    }
}

extern "C" void kernel_launch(void* const* d_in, const int* in_sizes, int n_in,
                              void* d_out, int out_size, void* d_ws, size_t ws_size,
                              hipStream_t stream) {
    const float* out_t = (const float*)d_in[0];
    const float* tgt   = (const float*)d_in[1];
    float* loss = (float*)d_out;
    float* partials = (float*)d_ws;            // NPART floats, fully rewritten
    int* ctr = (int*)((char*)d_ws + NPART * sizeof(float));

    hipMemsetAsync(ctr, 0, sizeof(int), stream);   // memset node: deterministic
    region_loss_fused<<<NPART, 256, 0, stream>>>(out_t, tgt, partials, ctr, loss);
}

// Round 4
// 32.421 us; speedup vs baseline: 2.2433x; 2.2433x over previous
//
#include <hip/hip_runtime.h>
#include <cstddef>

#define NB 64
#define NA 5
#define NC 20
#define NH 64
#define NW 64
#define MAXB 50
#define HWSZ (NH * NW)
#define CELLS 8
#define GBY 2                        // HWSZ / (256*CELLS)
#define NBB (NB * NA * GBY)          // 640 B-blocks
#define NPART (NBB + NB)             // + 64 A-blocks = 704

__constant__ float c_aw[NA] = {1.3221f, 3.19275f, 5.05587f, 9.47112f, 11.2364f};
__constant__ float c_ah[NA] = {1.73145f, 4.00944f, 8.09892f, 4.84053f, 10.0071f};

__device__ __forceinline__ float sigmoidf_(float v) {
    return 1.f / (1.f + __expf(-v));
}

__global__ __launch_bounds__(256) void region_loss_main(const float* __restrict__ out,
                                                        const float* __restrict__ tgt,
                                                        float* __restrict__ partials) {
    const int bid = blockIdx.x;
    const int t = threadIdx.x;

    __shared__ __align__(16) float sbox[MAXB][8];  // xlo,xhi,ylo,yhi,0.375*area
    __shared__ float s_cls[MAXB], s_gx[MAXB], s_gy[MAXB], s_gw[MAXB], s_gh[MAXB];
    __shared__ int s_flat[MAXB], s_bestn[MAXB];
    __shared__ int s_nv;
    __shared__ float sred[4];

    if (bid < NBB) {
        // ---------------- B: default no-obj conf loss over cells ----------------
        const int ba = bid >> 1;            // 0..319 = b*NA + a
        const int yc = bid & 1;
        const int b = ba / NA, a = ba % NA;
        const int hw0 = yc * (256 * CELLS);

        // wave 0: validity ballot + masked box staging (same wave, no sync needed)
        if (t < 64) {
            float xv = (t < MAXB) ? tgt[(size_t)b * (MAXB * 5) + t * 5 + 1] : 0.f;
            unsigned long long mk = __ballot(xv != 0.f);
            unsigned long long inv = (~mk) & ((1ull << MAXB) - 1ull);
            int nv = inv ? (__ffsll(inv) - 1) : MAXB;
            if (t < MAXB) {
                bool val = t < nv;
                const float* tp = tgt + (size_t)b * (MAXB * 5) + t * 5;
                float gx = tp[1] * (float)NW, gy = tp[2] * (float)NH;
                float gw = tp[3] * (float)NW, gh = tp[4] * (float)NH;
                sbox[t][0] = val ? gx - 0.5f * gw : 0.f;
                sbox[t][1] = val ? gx + 0.5f * gw : 0.f;
                sbox[t][2] = val ? gy - 0.5f * gh : 0.f;
                sbox[t][3] = val ? gy + 0.5f * gh : 0.f;
                sbox[t][4] = val ? 0.375f * gw * gh : 1e30f;  // masked: never silences
            }
        }

        float pxlo[CELLS], pxhi[CELLS], pylo[CELLS], pyhi[CELLS];
        float m[CELLS], rhs[CELLS], hc[CELLS];
        const float aw = c_aw[a], ah = c_ah[a];
        const float* p0 = out + (size_t)ba * 25 * HWSZ + hw0 + t;
#pragma unroll
        for (int c = 0; c < CELLS; ++c) {
            const int hw = hw0 + c * 256 + t;
            const float fi = (float)(hw & (NW - 1));
            const float fj = (float)(hw >> 6);
            const float* p = p0 + c * 256;
            float px = sigmoidf_(p[0]) + fi;
            float py = sigmoidf_(p[HWSZ]) + fj;
            float pw = __expf(p[2 * HWSZ]) * aw;
            float ph = __expf(p[3 * HWSZ]) * ah;
            float cf = sigmoidf_(p[4 * HWSZ]);
            pxlo[c] = px - 0.5f * pw; pxhi[c] = px + 0.5f * pw;
            pylo[c] = py - 0.5f * ph; pyhi[c] = py + 0.5f * ph;
            rhs[c] = 0.375f * pw * ph;
            hc[c]  = 0.5f * cf * cf;
            m[c]   = -1e30f;
        }
        __syncthreads();

        // fixed trip count -> compiler unrolls & pipelines the LDS reads
#pragma unroll 10
        for (int t2 = 0; t2 < MAXB; ++t2) {
            const float4 bb = *reinterpret_cast<const float4*>(&sbox[t2][0]);
            const float s2 = sbox[t2][4];
#pragma unroll
            for (int c = 0; c < CELLS; ++c) {
                float cw = fminf(pxhi[c], bb.y) - fmaxf(pxlo[c], bb.x);
                float ch = fminf(pyhi[c], bb.w) - fmaxf(pylo[c], bb.z);
                float ca = fmaxf(cw, 0.f) * fmaxf(ch, 0.f);
                m[c] = fmaxf(m[c], ca - s2);   // sil <=> max > 0.375*parea
            }
        }

        float v = 0.f;
#pragma unroll
        for (int c = 0; c < CELLS; ++c) v += (m[c] > rhs[c]) ? 0.f : hc[c];

        for (int off = 32; off; off >>= 1) v += __shfl_down(v, off, 64);
        if ((t & 63) == 0) sred[t >> 6] = v;
        __syncthreads();
        if (t == 0) partials[bid] = sred[0] + sred[1] + sred[2] + sred[3];
    } else {
        // ---------------- A: assigned-cell terms ----------------
        const int b = bid - NBB;
        if (t < 64) {
            float xv = (t < MAXB) ? tgt[(size_t)b * (MAXB * 5) + t * 5 + 1] : 0.f;
            unsigned long long mk = __ballot(xv != 0.f);
            if (t == 0) {
                unsigned long long inv = (~mk) & ((1ull << MAXB) - 1ull);
                s_nv = inv ? (__ffsll(inv) - 1) : MAXB;
            }
        }
        if (t < MAXB) {
            const float* tp = tgt + (size_t)b * (MAXB * 5) + t * 5;
            s_cls[t] = tp[0];
            s_gx[t] = tp[1] * NW; s_gy[t] = tp[2] * NH;
            s_gw[t] = tp[3] * NW; s_gh[t] = tp[4] * NH;
        }
        __syncthreads();
        const int nv = s_nv;

        if (t < MAXB) {
            if (t < nv) {
                float gw = s_gw[t], gh = s_gh[t];
                float best = -1.f; int bn = 0;
                for (int a = 0; a < NA; ++a) {
                    float ca = fminf(c_aw[a], gw) * fminf(c_ah[a], gh);
                    float ua = c_aw[a] * c_ah[a] + gw * gh - ca;
                    float iou = ca / ua;
                    if (iou > best) { best = iou; bn = a; }   // first max wins
                }
                int gi = (int)s_gx[t], gj = (int)s_gy[t];
                s_bestn[t] = bn;
                s_flat[t] = (bn * NH + gj) * NW + gi;
            } else {
                s_flat[t] = -1 - t;
            }
        }
        __syncthreads();

        float loss = 0.f;
        if (t < nv) {
            // last-writer-wins dedupe (matches serial scatter order)
            bool winner = true;
            const int myf = s_flat[t];
            for (int t2 = t + 1; t2 < nv; ++t2) winner = winner && (s_flat[t2] != myf);
            if (winner) {
                const int a = s_bestn[t];
                const int gi = myf & (NW - 1);
                const int gj = (myf >> 6) & (NH - 1);
                const size_t base = (((size_t)b * NA + a) * 25) * HWSZ + gj * NW + gi;
                float x = sigmoidf_(out[base]);
                float y = sigmoidf_(out[base + HWSZ]);
                float w = __expf(out[base + 2 * HWSZ]);
                float h = __expf(out[base + 3 * HWSZ]);
                float conf = sigmoidf_(out[base + 4 * HWSZ]);

                float gx = s_gx[t], gy = s_gy[t], gw = s_gw[t], gh = s_gh[t];
                float tx = gx - (float)gi, ty = gy - (float)gj;
                float tw = gw / c_aw[a], th = gh / c_ah[a];
                float dx = x - tx, dy = y - ty, dw = w - tw, dh = h - th;
                loss += 0.5f * (dx * dx + dy * dy + dw * dw + dh * dh);

                float px = x + (float)gi, py = y + (float)gj;
                float pw = w * c_aw[a], ph = h * c_ah[a];
                float pxlo = px - 0.5f * pw, pxhi = px + 0.5f * pw;
                float pylo = py - 0.5f * ph, pyhi = py + 0.5f * ph;
                float parea = pw * ph;

                {   // assigned conf term minus what B added for this cell
                    float cw  = fminf(pxhi, gx + 0.5f * gw) - fmaxf(pxlo, gx - 0.5f * gw);
                    float chh = fminf(pyhi, gy + 0.5f * gh) - fmaxf(pylo, gy - 0.5f * gh);
                    float ca  = fmaxf(cw, 0.f) * fmaxf(chh, 0.f);
                    float ua  = parea + gw * gh - ca;
                    float tconf = ca / ua;
                    float mm = -1e30f;
                    for (int t2 = 0; t2 < nv; ++t2) {
                        float gw2 = s_gw[t2], gh2 = s_gh[t2];
                        float cw2 = fminf(pxhi, s_gx[t2] + 0.5f * gw2) -
                                    fmaxf(pxlo, s_gx[t2] - 0.5f * gw2);
                        float ch2 = fminf(pyhi, s_gy[t2] + 0.5f * gh2) -
                                    fmaxf(pylo, s_gy[t2] - 0.5f * gh2);
                        float ca2 = fmaxf(cw2, 0.f) * fmaxf(ch2, 0.f);
                        mm = fmaxf(mm, ca2 - 0.375f * gw2 * gh2);
                    }
                    bool sil = mm > 0.375f * parea;
                    float base_c = sil ? 0.f : 0.5f * conf * conf;
                    float dc = conf - tconf;
                    loss += 0.5f * dc * dc - base_c;
                }

                {   // class cross-entropy
                    const int lab = (int)s_cls[t];
                    float mmax = -1e30f, llab = 0.f;
                    for (int c = 0; c < NC; ++c) {
                        float l = out[base + (size_t)(5 + c) * HWSZ];
                        mmax = fmaxf(mmax, l);
                        if (c == lab) llab = l;
                    }
                    float se = 0.f;
                    for (int c = 0; c < NC; ++c)
                        se += __expf(out[base + (size_t)(5 + c) * HWSZ] - mmax);
                    loss += -(llab - mmax - logf(se));
                }
            }
        }
        for (int off = 32; off; off >>= 1) loss += __shfl_down(loss, off, 64);
        if (t == 0) partials[bid] = loss;
    }
}

// ---------------- deterministic final reduce (2nd graph node) ----------------
__global__ __launch_bounds__(256) void reduce_kernel(const float* __restrict__ partials,
                                                     float* __restrict__ outp) {
    float v = 0.f;
    for (int idx = threadIdx.x; idx < NPART; idx += 256) v += partials[idx];
    for (int off = 32; off; off >>= 1) v += __shfl_down(v, off, 64);
    __shared__ float s[4];
    if ((threadIdx.x & 63) == 0) s[threadIdx.x >> 6] = v;
    __syncthreads();
    if (threadIdx.x == 0) outp[0] = s[0] + s[1] + s[2] + s[3];
}

extern "C" void kernel_launch(void* const* d_in, const int* in_sizes, int n_in,
                              void* d_out, int out_size, void* d_ws, size_t ws_size,
                              hipStream_t stream) {
    const float* out_t = (const float*)d_in[0];
    const float* tgt   = (const float*)d_in[1];
    float* loss = (float*)d_out;
    float* partials = (float*)d_ws;   // NPART floats, fully rewritten each call

    region_loss_main<<<NPART, 256, 0, stream>>>(out_t, tgt, partials);
    reduce_kernel<<<1, 256, 0, stream>>>(partials, loss);
}